// Round 2
// baseline (2530.724 us; speedup 1.0000x reference)
//
#include <hip/hip_runtime.h>
#include <math.h>

#define NLAT 91
#define NLON 180
#define NCH  64
#define KSZ  25
#define NW   9
#define HALF 4
#define NB   2
#define CG   4
#define CPG  16   // NCH / CG
#define THREADS 192
#define MASK_BYTES (NLAT * NW * NLON)

#ifndef M_PI
#define M_PI 3.14159265358979323846
#endif

// ---------------------------------------------------------------------------
// HOST: replicate numpy's inside-decision bit-exactly (glibc libm, exact
// IEEE op order, no FMA contraction). Only the BOOLEAN r<=cutoff & valid is
// implementation-sensitive; psi *values* are computed on device (1-ulp f64
// diffs vanish at the f32 cast).
// ---------------------------------------------------------------------------
static void compute_mask_host(unsigned char* mask)
{
#pragma clang fp contract(off)
    double sth[NLAT], cth[NLAT], cph[NLON];
    for (int t = 0; t < NLAT; t++) {
        double th = (M_PI * (double)t) / 90.0;   // == np.pi*arange/90 elementwise
        sth[t] = sin(th);
        cth[t] = cos(th);
    }
    for (int q = 0; q < NLON; q++) {
        double ph = (2.0 * M_PI * (double)q) / 180.0;
        cph[q] = cos(ph);
    }
    const double cutoff = (4.0 * M_PI) / 90.0;
    for (int t = 0; t < NLAT; t++) {
        for (int w = 0; w < NW; w++) {
            int ti_raw = t - HALF + w;
            int valid = (ti_raw >= 0) && (ti_raw < NLAT);
            int ti = ti_raw < 0 ? 0 : (ti_raw > NLAT - 1 ? NLAT - 1 : ti_raw);
            for (int q = 0; q < NLON; q++) {
                double t1 = sth[t] * sth[ti];   // sin(to)*sin(ti)
                double t2 = t1 * cph[q];        // *cos(ph)
                double t3 = cth[t] * cth[ti];   // cos(to)*cos(ti)
                double zz = t2 + t3;
                if (zz > 1.0) zz = 1.0;
                if (zz < -1.0) zz = -1.0;
                double r = acos(zz);
                mask[(t * NW + w) * NLON + q] =
                    (valid && (r <= cutoff)) ? 1 : 0;
            }
        }
    }
}

// ---------------------------------------------------------------------------
// Kernel 1: build psi values [t][w][q][k] (quad folded in), inclusion taken
// from the host mask; per-(t,w) window half-width qmax (-1 if empty).
// ---------------------------------------------------------------------------
__global__ __launch_bounds__(THREADS) void build_psi(float* __restrict__ psi_c,
                                                     int* __restrict__ qmax,
                                                     const unsigned char* __restrict__ mask)
{
    int t = blockIdx.x, w = blockIdx.y;
    int q = threadIdx.x;
    __shared__ int red[THREADS];
    int myq = -1;
    if (q < NLON) {
        int ti_raw = t - HALF + w;
        int ti = ti_raw < 0 ? 0 : (ti_raw > NLAT - 1 ? NLAT - 1 : ti_raw);
        double to  = (M_PI * (double)t) / 90.0;
        double tin = (M_PI * (double)ti) / 90.0;
        double ph  = (2.0 * M_PI * (double)q) / 180.0;
        double sto = sin(to), cto = cos(to);
        double sti = sin(tin), cti = cos(tin);
        double cphv = cos(ph), sphv = sin(ph);
        double xx = cto * sti * cphv - sto * cti;
        double yy = sti * sphv;
        double zz = sto * sti * cphv + cto * cti;
        zz = fmin(1.0, fmax(-1.0, zz));
        double r = acos(zz);
        const double cutoff = (4.0 * M_PI) / 90.0;
        const double drr   = cutoff / 4.0;       // NR-1 = 4
        const double dphi  = (2.0 * M_PI) / 6.0; // NPHI = 6
        double scale = mask[(t * NW + w) * NLON + q] ? 1.0 : 0.0;
        double quad = sin(tin) * (M_PI / 90.0) * ((2.0 * M_PI) / 180.0);
        double sq = scale * quad;
        double phi = atan2(yy, xx);
        phi = fmod(phi, 2.0 * M_PI);
        if (phi < 0.0) phi += 2.0 * M_PI;
        float* dst = psi_c + (((size_t)(t * NW + w)) * NLON + q) * KSZ;
        double psi0 = fmax(0.0, 1.0 - r / drr);
        dst[0] = (float)(psi0 * sq);
        for (int ir = 1; ir < 5; ir++) {
            double rad = fmax(0.0, 1.0 - fabs(r - ir * drr) / drr);
            for (int ip = 0; ip < 6; ip++) {
                double m = fmod(phi - ip * dphi + M_PI, 2.0 * M_PI);
                if (m < 0.0) m += 2.0 * M_PI;
                double dp = fabs(m - M_PI);
                double ang = fmax(0.0, 1.0 - dp / dphi);
                dst[1 + (ir - 1) * 6 + ip] = (float)(rad * ang * sq);
            }
        }
        if (sq != 0.0) {
            myq = (q <= 90) ? q : (NLON - q);   // wrapped |dq|
        }
    }
    red[threadIdx.x] = myq;
    __syncthreads();
    for (int s = 128; s > 0; s >>= 1) {
        if (threadIdx.x < s && threadIdx.x + s < THREADS)
            red[threadIdx.x] = max(red[threadIdx.x], red[threadIdx.x + s]);
        __syncthreads();
    }
    if (threadIdx.x == 0) qmax[t * NW + w] = red[0];
}

// ---------------------------------------------------------------------------
// Kernel 2: fused sparse-correlation + weight contraction.
// Block = (c-group, t, b); thread owns longitude p.
// ---------------------------------------------------------------------------
__global__ __launch_bounds__(THREADS) void disco_fused(
    const float* __restrict__ x, const float* __restrict__ wgt,
    const float* __restrict__ psi_c, const int* __restrict__ qmax,
    float* __restrict__ part)
{
    int cg = blockIdx.x, t = blockIdx.y, b = blockIdx.z;
    int tid = threadIdx.x;
    int p = tid < NLON ? tid : NLON - 1;
    bool act = tid < NLON;
    int i0 = (t - HALF < 0) ? 0 : t - HALF;
    int i1 = (t + HALF > NLAT - 1) ? NLAT - 1 : t + HALF;
    int nrows = i1 - i0 + 1;

    __shared__ float xs[NW * NLON];

    float acc[NCH];
#pragma unroll
    for (int o = 0; o < NCH; o++) acc[o] = 0.f;

    for (int ci = 0; ci < CPG; ci++) {
        int c = cg * CPG + ci;
        __syncthreads();
        const float* xsrc = x + ((size_t)(b * NCH + c) * NLAT + i0) * NLON;
        for (int e = tid; e < nrows * NLON; e += THREADS) xs[e] = xsrc[e];
        __syncthreads();

        float z[KSZ];
#pragma unroll
        for (int k = 0; k < KSZ; k++) z[k] = 0.f;

        for (int w = 0; w < NW; w++) {
            int qm = qmax[t * NW + w];
            if (qm < 0) continue;
            int tw = t - HALF + w;
            int ti = tw < 0 ? 0 : (tw > NLAT - 1 ? NLAT - 1 : tw);
            const float* xrow = xs + (ti - i0) * NLON;
            const float* ps = psi_c + ((size_t)(t * NW + w)) * NLON * KSZ;
            int lo = -(qm > 89 ? 89 : qm), hi = qm;
            for (int dq = lo; dq <= hi; dq++) {
                int q = dq < 0 ? dq + NLON : dq;
                int pp = p + dq;
                if (pp < 0) pp += NLON;
                if (pp >= NLON) pp -= NLON;
                float xv = xrow[pp];
                const float* pk = ps + q * KSZ;
#pragma unroll
                for (int k = 0; k < KSZ; k++) z[k] = fmaf(pk[k], xv, z[k]);
            }
        }

        // stage 2: acc[o] += sum_k wgt[o][c][k] * z[k]  (full unroll — keep
        // acc[] statically indexed, no scratch)
        const float* wc = wgt + (size_t)c * KSZ;
#pragma unroll
        for (int o = 0; o < NCH; o++) {
            const float* wk = wc + (size_t)o * NCH * KSZ;
            float s = 0.f;
#pragma unroll
            for (int k = 0; k < KSZ; k++) s = fmaf(wk[k], z[k], s);
            acc[o] += s;
        }
    }

    if (act) {
        float* dst = part + ((((size_t)cg * NB + b) * NCH) * NLAT + t) * NLON + p;
#pragma unroll
        for (int o = 0; o < NCH; o++) dst[(size_t)o * NLAT * NLON] = acc[o];
    }
}

// ---------------------------------------------------------------------------
// Kernel 3: sum the CG partials into d_out.
// ---------------------------------------------------------------------------
__global__ void reduce_part(const float* __restrict__ part,
                            float* __restrict__ out, int n4)
{
    int i = blockIdx.x * blockDim.x + threadIdx.x;
    if (i >= n4) return;
    const float4* p4 = (const float4*)part;
    float4 a = p4[i];
    float4 b = p4[i + (size_t)n4];
    float4 c = p4[i + 2 * (size_t)n4];
    float4 d = p4[i + 3 * (size_t)n4];
    float4 r;
    r.x = a.x + b.x + c.x + d.x;
    r.y = a.y + b.y + c.y + d.y;
    r.z = a.z + b.z + c.z + d.z;
    r.w = a.w + b.w + c.w + d.w;
    ((float4*)out)[i] = r;
}

extern "C" void kernel_launch(void* const* d_in, const int* in_sizes, int n_in,
                              void* d_out, int out_size, void* d_ws, size_t ws_size,
                              hipStream_t stream)
{
    const float* x   = (const float*)d_in[0];
    const float* wgt = (const float*)d_in[1];
    char* ws = (char*)d_ws;

    size_t psi_bytes  = (size_t)NLAT * NW * NLON * KSZ * sizeof(float); // ~14.7 MB
    size_t off1 = (psi_bytes + 255) & ~(size_t)255;
    size_t qmax_bytes = (size_t)NLAT * NW * sizeof(int);
    size_t off2 = (off1 + qmax_bytes + 255) & ~(size_t)255;
    size_t off3 = (off2 + MASK_BYTES + 255) & ~(size_t)255;

    float* psi_c = (float*)ws;
    int*   qmaxb = (int*)(ws + off1);
    unsigned char* d_mask = (unsigned char*)(ws + off2);
    float* part  = (float*)(ws + off3);   // CG * 2.1M floats = 33.5 MB

    // Host-side inclusion mask (recomputed every call — deterministic, same
    // values; static storage keeps the pointer valid for graph replay).
    static unsigned char h_mask[MASK_BYTES];
    compute_mask_host(h_mask);
    hipMemcpyAsync(d_mask, h_mask, MASK_BYTES, hipMemcpyHostToDevice, stream);

    build_psi<<<dim3(NLAT, NW), THREADS, 0, stream>>>(psi_c, qmaxb, d_mask);
    disco_fused<<<dim3(CG, NLAT, NB), THREADS, 0, stream>>>(x, wgt, psi_c, qmaxb, part);

    int n  = NB * NCH * NLAT * NLON;   // 2,096,640
    int n4 = n / 4;                    // 524,160
    reduce_part<<<(n4 + 255) / 256, 256, 0, stream>>>(part, (float*)d_out, n4);
}

// Round 3
// 1727.865 us; speedup vs baseline: 1.4647x; 1.4647x over previous
//
#include <hip/hip_runtime.h>
#include <math.h>

#define NLAT 91
#define NLON 180
#define NCH  64
#define KSZ  25
#define NW   9
#define HALF 4
#define NB   2
#define CG   4
#define CPG  16   // NCH / CG
#define THREADS 192
#define TCAP 4608        // packed entries per t (worst-case pole ~3000)
#define KCAP 512         // staging capacity per (t,k)
#define XW   360         // doubled x row width (circular indexing -> one add)
#define MASK_BYTES (NLAT * NW * NLON)

#ifndef M_PI
#define M_PI 3.14159265358979323846
#endif

// ---------------------------------------------------------------------------
// HOST: numpy-bit-exact inclusion mask (glibc libm, exact IEEE op order).
// ---------------------------------------------------------------------------
static void compute_mask_host(unsigned char* mask)
{
#pragma clang fp contract(off)
    double sth[NLAT], cth[NLAT], cph[NLON];
    for (int t = 0; t < NLAT; t++) {
        double th = (M_PI * (double)t) / 90.0;
        sth[t] = sin(th);
        cth[t] = cos(th);
    }
    for (int q = 0; q < NLON; q++) {
        double ph = (2.0 * M_PI * (double)q) / 180.0;
        cph[q] = cos(ph);
    }
    const double cutoff = (4.0 * M_PI) / 90.0;
    for (int t = 0; t < NLAT; t++)
        for (int w = 0; w < NW; w++) {
            int ti_raw = t - HALF + w;
            int valid = (ti_raw >= 0) && (ti_raw < NLAT);
            int ti = ti_raw < 0 ? 0 : (ti_raw > NLAT - 1 ? NLAT - 1 : ti_raw);
            for (int q = 0; q < NLON; q++) {
                double t1 = sth[t] * sth[ti];
                double t2 = t1 * cph[q];
                double t3 = cth[t] * cth[ti];
                double zz = t2 + t3;
                if (zz > 1.0) zz = 1.0;
                if (zz < -1.0) zz = -1.0;
                double r = acos(zz);
                mask[(t * NW + w) * NLON + q] = (valid && (r <= cutoff)) ? 1 : 0;
            }
        }
}

// ---------------------------------------------------------------------------
// Kernel 1: dense psi values [t][w][q][25] (quad folded in), host mask gates.
// ---------------------------------------------------------------------------
__global__ __launch_bounds__(THREADS) void build_psi(float* __restrict__ psi_c,
                                                     const unsigned char* __restrict__ mask)
{
    int t = blockIdx.x, w = blockIdx.y;
    int q = threadIdx.x;
    if (q >= NLON) return;
    int ti_raw = t - HALF + w;
    int ti = ti_raw < 0 ? 0 : (ti_raw > NLAT - 1 ? NLAT - 1 : ti_raw);
    double to  = (M_PI * (double)t) / 90.0;
    double tin = (M_PI * (double)ti) / 90.0;
    double ph  = (2.0 * M_PI * (double)q) / 180.0;
    double sto = sin(to), cto = cos(to);
    double sti = sin(tin), cti = cos(tin);
    double cphv = cos(ph), sphv = sin(ph);
    double xx = cto * sti * cphv - sto * cti;
    double yy = sti * sphv;
    double zz = sto * sti * cphv + cto * cti;
    zz = fmin(1.0, fmax(-1.0, zz));
    double r = acos(zz);
    const double cutoff = (4.0 * M_PI) / 90.0;
    const double drr   = cutoff / 4.0;
    const double dphi  = (2.0 * M_PI) / 6.0;
    double scale = mask[(t * NW + w) * NLON + q] ? 1.0 : 0.0;
    double quad = sin(tin) * (M_PI / 90.0) * ((2.0 * M_PI) / 180.0);
    double sq = scale * quad;
    double phi = atan2(yy, xx);
    phi = fmod(phi, 2.0 * M_PI);
    if (phi < 0.0) phi += 2.0 * M_PI;
    float* dst = psi_c + (((size_t)(t * NW + w)) * NLON + q) * KSZ;
    double psi0 = fmax(0.0, 1.0 - r / drr);
    dst[0] = (float)(psi0 * sq);
    for (int ir = 1; ir < 5; ir++) {
        double rad = fmax(0.0, 1.0 - fabs(r - ir * drr) / drr);
        for (int ip = 0; ip < 6; ip++) {
            double m = fmod(phi - ip * dphi + M_PI, 2.0 * M_PI);
            if (m < 0.0) m += 2.0 * M_PI;
            double dp = fabs(m - M_PI);
            double ang = fmax(0.0, 1.0 - dp / dphi);
            dst[1 + (ir - 1) * 6 + ip] = (float)(rad * ang * sq);
        }
    }
}

// ---------------------------------------------------------------------------
// Kernel 1b: transpose weights [o][c][k] -> wt[c][k][o] (contiguous o for
// uniform s_load chains in stage 2).
// ---------------------------------------------------------------------------
__global__ void transpose_w(const float* __restrict__ wgt, float* __restrict__ wt)
{
    int i = blockIdx.x * blockDim.x + threadIdx.x;
    if (i >= NCH * NCH * KSZ) return;
    int o = i / (NCH * KSZ);
    int rem = i - o * (NCH * KSZ);
    int c = rem / KSZ;
    int k = rem - c * KSZ;
    wt[((size_t)c * KSZ + k) * NCH + o] = wgt[i];
}

// ---------------------------------------------------------------------------
// Kernel 1c: compact dense psi into per-t, per-k CSR entry lists.
// Entry = (u16 LDS-elem offset = w*360 + dq + 90, f32 value).
// Each k-list padded to a multiple of 4 with (0,0) entries -> no tail loop,
// 16B-aligned float4/ushort4 LDS reads in the main kernel.
// ---------------------------------------------------------------------------
__global__ __launch_bounds__(64) void compact_psi(
    const float* __restrict__ psi_c,
    float* __restrict__ tmpv, int* __restrict__ tmpo,
    int* __restrict__ koff,
    float* __restrict__ gvals, unsigned short* __restrict__ goffs)
{
    int t = blockIdx.x;
    __shared__ int scnt[KSZ];
    __shared__ int soff[KSZ + 1];
    int k = threadIdx.x;
    if (k < KSZ) {
        int cnt = 0;
        float* tv = tmpv + ((size_t)t * KSZ + k) * KCAP;
        int*   to = tmpo + ((size_t)t * KSZ + k) * KCAP;
        for (int w = 0; w < NW; w++) {
            const float* base = psi_c + (((size_t)(t * NW + w)) * NLON) * KSZ + k;
            for (int q = 0; q < NLON; q++) {
                float v = base[q * KSZ];
                if (v != 0.f && cnt < KCAP) {
                    int dq = (q <= 90) ? q : q - NLON;
                    tv[cnt] = v;
                    to[cnt] = w * XW + dq + 90;
                    cnt++;
                }
            }
        }
        scnt[k] = cnt;
    }
    __syncthreads();
    if (threadIdx.x == 0) {
        int o = 0;
        for (int kk = 0; kk < KSZ; kk++) { soff[kk] = o; o += (scnt[kk] + 3) & ~3; }
        soff[KSZ] = o;
        for (int kk = 0; kk <= KSZ; kk++) koff[t * (KSZ + 1) + kk] = soff[kk];
    }
    __syncthreads();
    for (int kk = 0; kk < KSZ; kk++) {
        int cnt = scnt[kk], off = soff[kk], pad = (cnt + 3) & ~3;
        const float* tv = tmpv + ((size_t)t * KSZ + kk) * KCAP;
        const int*   to = tmpo + ((size_t)t * KSZ + kk) * KCAP;
        for (int i = threadIdx.x; i < pad; i += 64) {
            gvals[(size_t)t * TCAP + off + i] = (i < cnt) ? tv[i] : 0.f;
            goffs[(size_t)t * TCAP + off + i] = (i < cnt) ? (unsigned short)to[i] : (unsigned short)0;
        }
    }
}

// ---------------------------------------------------------------------------
// Kernel 2: main fused kernel. Block=(cg,t,b); thread owns longitude p.
// Per channel: stage doubled x rows in LDS; per k, run the CSR list with
// 4-wide unrolled gather-FMA (broadcast entry reads, lane-consecutive x
// gathers -> conflict-free); stage-2 contraction into acc[64] with uniform
// contiguous weight loads.
// ---------------------------------------------------------------------------
__global__ __launch_bounds__(THREADS) void disco_main(
    const float* __restrict__ x, const float* __restrict__ wt,
    const float* __restrict__ gvals, const unsigned short* __restrict__ goffs,
    const int* __restrict__ koff, float* __restrict__ part)
{
    int cg = blockIdx.x, t = blockIdx.y, b = blockIdx.z;
    int tid = threadIdx.x;
    int p = tid < NLON ? tid : NLON - 1;
    bool act = tid < NLON;

    __shared__ float xs[NW * XW];                       // 12.96 KB
    __shared__ __align__(16) float evals[TCAP];         // 18 KB
    __shared__ __align__(16) unsigned short eoffs[TCAP];// 9 KB
    __shared__ int skoff[KSZ + 1];

    if (tid <= KSZ) skoff[tid] = koff[t * (KSZ + 1) + tid];
    __syncthreads();
    int nent = skoff[KSZ];
    for (int e = tid; e < nent; e += THREADS) {
        evals[e] = gvals[(size_t)t * TCAP + e];
        eoffs[e] = goffs[(size_t)t * TCAP + e];
    }
    // (first __syncthreads inside ci loop covers these writes)

    float acc[NCH];
#pragma unroll
    for (int o = 0; o < NCH; o++) acc[o] = 0.f;

    for (int ci = 0; ci < CPG; ci++) {
        int c = cg * CPG + ci;
        __syncthreads();
        const float* xc = x + ((size_t)(b * NCH + c)) * NLAT * NLON;
        for (int j = tid; j < NW * XW; j += THREADS) {
            int w = j / XW;
            int jj = j - w * XW;
            int tw = t - HALF + w;
            int ti = tw < 0 ? 0 : (tw > NLAT - 1 ? NLAT - 1 : tw);
            int src = jj + 90;
            if (src >= NLON) src -= NLON;
            if (src >= NLON) src -= NLON;
            xs[j] = xc[ti * NLON + src];
        }
        __syncthreads();

        const float* wrow = wt + (size_t)c * (KSZ * NCH);
        for (int k = 0; k < KSZ; k++) {
            int e0 = skoff[k], e1 = skoff[k + 1];
            float z0 = 0.f, z1 = 0.f, z2 = 0.f, z3 = 0.f;
            for (int e = e0; e < e1; e += 4) {
                float4  v  = *(const float4*)&evals[e];
                ushort4 o4 = *(const ushort4*)&eoffs[e];
                z0 = fmaf(v.x, xs[(int)o4.x + p], z0);
                z1 = fmaf(v.y, xs[(int)o4.y + p], z1);
                z2 = fmaf(v.z, xs[(int)o4.z + p], z2);
                z3 = fmaf(v.w, xs[(int)o4.w + p], z3);
            }
            float zk = (z0 + z1) + (z2 + z3);
            const float* wk = wrow + k * NCH;
#pragma unroll
            for (int o = 0; o < NCH; o++)
                acc[o] = fmaf(wk[o], zk, acc[o]);
        }
    }

    if (act) {
        float* dst = part + ((((size_t)cg * NB + b) * NCH) * NLAT + t) * NLON + p;
#pragma unroll
        for (int o = 0; o < NCH; o++) dst[(size_t)o * NLAT * NLON] = acc[o];
    }
}

// ---------------------------------------------------------------------------
// Kernel 3: sum the CG partials into d_out.
// ---------------------------------------------------------------------------
__global__ void reduce_part(const float* __restrict__ part,
                            float* __restrict__ out, int n4)
{
    int i = blockIdx.x * blockDim.x + threadIdx.x;
    if (i >= n4) return;
    const float4* p4 = (const float4*)part;
    float4 a = p4[i];
    float4 b = p4[i + (size_t)n4];
    float4 c = p4[i + 2 * (size_t)n4];
    float4 d = p4[i + 3 * (size_t)n4];
    float4 r;
    r.x = a.x + b.x + c.x + d.x;
    r.y = a.y + b.y + c.y + d.y;
    r.z = a.z + b.z + c.z + d.z;
    r.w = a.w + b.w + c.w + d.w;
    ((float4*)out)[i] = r;
}

extern "C" void kernel_launch(void* const* d_in, const int* in_sizes, int n_in,
                              void* d_out, int out_size, void* d_ws, size_t ws_size,
                              hipStream_t stream)
{
    const float* x   = (const float*)d_in[0];
    const float* wgt = (const float*)d_in[1];
    char* ws = (char*)d_ws;

    // Region A (33.5 MB): psi | tmpv | tmpo live only during build/compact;
    // the same bytes later hold the CG partials written by disco_main.
    size_t psi_bytes  = (size_t)NLAT * NW * NLON * KSZ * sizeof(float);   // 14.74 MB
    size_t tmpv_off   = (psi_bytes + 255) & ~(size_t)255;
    size_t tmpv_bytes = (size_t)NLAT * KSZ * KCAP * sizeof(float);        // 4.66 MB
    size_t tmpo_off   = (tmpv_off + tmpv_bytes + 255) & ~(size_t)255;
    size_t tmpo_bytes = (size_t)NLAT * KSZ * KCAP * sizeof(int);          // 4.66 MB
    size_t part_bytes = (size_t)CG * NB * NCH * NLAT * NLON * sizeof(float); // 33.5 MB
    size_t regA = part_bytes;
    size_t tail = (tmpo_off + tmpo_bytes);
    if (tail > regA) regA = tail;
    regA = (regA + 255) & ~(size_t)255;

    size_t mask_off  = regA;
    size_t gvals_off = (mask_off + MASK_BYTES + 255) & ~(size_t)255;
    size_t goffs_off = (gvals_off + (size_t)NLAT * TCAP * sizeof(float) + 255) & ~(size_t)255;
    size_t koff_off  = (goffs_off + (size_t)NLAT * TCAP * sizeof(unsigned short) + 255) & ~(size_t)255;
    size_t wt_off    = (koff_off + (size_t)NLAT * (KSZ + 1) * sizeof(int) + 255) & ~(size_t)255;

    float*          psi_c  = (float*)ws;
    float*          tmpv   = (float*)(ws + tmpv_off);
    int*            tmpo   = (int*)(ws + tmpo_off);
    float*          part   = (float*)ws;
    unsigned char*  d_mask = (unsigned char*)(ws + mask_off);
    float*          gvals  = (float*)(ws + gvals_off);
    unsigned short* goffs  = (unsigned short*)(ws + goffs_off);
    int*            koffb  = (int*)(ws + koff_off);
    float*          wt     = (float*)(ws + wt_off);

    static unsigned char h_mask[MASK_BYTES];
    compute_mask_host(h_mask);
    hipMemcpyAsync(d_mask, h_mask, MASK_BYTES, hipMemcpyHostToDevice, stream);

    build_psi<<<dim3(NLAT, NW), THREADS, 0, stream>>>(psi_c, d_mask);
    transpose_w<<<(NCH * NCH * KSZ + 255) / 256, 256, 0, stream>>>(wgt, wt);
    compact_psi<<<NLAT, 64, 0, stream>>>(psi_c, tmpv, tmpo, koffb, gvals, goffs);
    disco_main<<<dim3(CG, NLAT, NB), THREADS, 0, stream>>>(x, wt, gvals, goffs, koffb, part);

    int n  = NB * NCH * NLAT * NLON;   // 2,096,640
    int n4 = n / 4;                    // 524,160
    reduce_part<<<(n4 + 255) / 256, 256, 0, stream>>>(part, (float*)d_out, n4);
}

// Round 4
// 490.100 us; speedup vs baseline: 5.1637x; 3.5255x over previous
//
#include <hip/hip_runtime.h>
#include <math.h>
#include <string.h>

#define NLAT 91
#define NLON 180
#define NCH  64
#define KSZ  25
#define NW   9
#define HALF 4
#define NB   2
#define CG   4
#define CPG  16     // NCH / CG
#define THREADS 192
#define XW   360    // doubled row width
#define EUNIT 512   // entries per balanced work unit (multiple of 8)
#define ENT_CAP 262144
#define UCAP 1024
#define LCAP 1024   // per-(t,k) list cap

#define KOFF_OFF 0
#define KOFF_BYTES (NLAT * (KSZ + 1) * 4)     // 9464
#define UNITS_OFF 9728                         // 256-aligned
#define UNITS_BYTES (UCAP * 16)                // 16384
#define ENTS_OFF (UNITS_OFF + UNITS_BYTES)     // 26112 (64B-aligned)

#ifndef M_PI
#define M_PI 3.14159265358979323846
#endif

typedef unsigned int u32;

// ---------------------------------------------------------------------------
// HOST: build compressed DISCO tables bit-compatibly with the numpy reference
// (glibc libm, exact IEEE op order, contraction off). Entries are grouped per
// (t,k), padded to multiples of 8 with zero entries; units are fixed 512-entry
// windows (load-balanced across latitudes).
// ---------------------------------------------------------------------------
static int build_tables(unsigned char* blob, int* ne_out)
{
#pragma clang fp contract(off)
    int* koff  = (int*)(blob + KOFF_OFF);
    u32* units = (u32*)(blob + UNITS_OFF);
    u32* ents  = (u32*)(blob + ENTS_OFF);   // pairs {off, f32 bits}

    static double sth[NLAT], cth[NLAT], cphv[NLON], sphv[NLON];
    for (int t = 0; t < NLAT; t++) {
        double th = (M_PI * (double)t) / 90.0;
        sth[t] = sin(th); cth[t] = cos(th);
    }
    for (int q = 0; q < NLON; q++) {
        double ph = (2.0 * M_PI * (double)q) / 180.0;
        cphv[q] = cos(ph); sphv[q] = sin(ph);
    }
    const double cutoff = (4.0 * M_PI) / 90.0;
    const double dr     = cutoff / 4.0;         // NR-1 = 4
    const double dphi   = (2.0 * M_PI) / 6.0;   // NPHI = 6

    static int   lcnt[KSZ];
    static u32   loff_[KSZ][LCAP];
    static float lval[KSZ][LCAP];

    int ne = 0, nu = 0;
    for (int t = 0; t < NLAT; t++) {
        for (int k = 0; k < KSZ; k++) lcnt[k] = 0;
        for (int w = 0; w < NW; w++) {
            int ti_raw = t - HALF + w;
            int valid = (ti_raw >= 0) && (ti_raw < NLAT);
            int ti = ti_raw < 0 ? 0 : (ti_raw > NLAT - 1 ? NLAT - 1 : ti_raw);
            for (int q = 0; q < NLON; q++) {
                double t1 = sth[t] * sth[ti];
                double t2 = t1 * cphv[q];
                double t3 = cth[t] * cth[ti];
                double zz = t2 + t3;
                if (zz > 1.0) zz = 1.0;
                if (zz < -1.0) zz = -1.0;
                double r = acos(zz);
                if (!(valid && (r <= cutoff))) continue;
                double xx = (cth[t] * sth[ti]) * cphv[q] - sth[t] * cth[ti];
                double yy = sth[ti] * sphv[q];
                double phi = atan2(yy, xx);
                { double m = fmod(phi, 2.0 * M_PI); if (m < 0.0) m += 2.0 * M_PI; phi = m; }
                double quad = sth[ti] * (M_PI / 90.0) * ((2.0 * M_PI) / 180.0);
                int dq = (q <= 90) ? q : q - NLON;
                u32 off = (u32)(w * XW + 90 + dq);
                double v0 = fmax(0.0, 1.0 - r / dr);
                float f0 = (float)(v0 * quad);
                if (f0 != 0.f && lcnt[0] < LCAP) {
                    loff_[0][lcnt[0]] = off; lval[0][lcnt[0]] = f0; lcnt[0]++;
                }
                for (int ir = 1; ir < 5; ir++) {
                    double rad = fmax(0.0, 1.0 - fabs(r - ir * dr) / dr);
                    for (int ip = 0; ip < 6; ip++) {
                        double a = (phi - ip * dphi) + M_PI;
                        double m = fmod(a, 2.0 * M_PI);
                        if (m < 0.0) m += 2.0 * M_PI;
                        double dp = fabs(m - M_PI);
                        double ang = fmax(0.0, 1.0 - dp / dphi);
                        float f = (float)((rad * ang) * quad);
                        int k = 1 + (ir - 1) * 6 + ip;
                        if (f != 0.f && lcnt[k] < LCAP) {
                            loff_[k][lcnt[k]] = off; lval[k][lcnt[k]] = f; lcnt[k]++;
                        }
                    }
                }
            }
        }
        int tBase = ne;
        for (int k = 0; k < KSZ; k++) {
            koff[t * (KSZ + 1) + k] = ne;
            for (int i = 0; i < lcnt[k] && ne < ENT_CAP; i++) {
                ents[2 * ne] = loff_[k][i];
                ents[2 * ne + 1] = __builtin_bit_cast(u32, lval[k][i]);
                ne++;
            }
            while (((ne - koff[t * (KSZ + 1) + k]) & 7) && ne < ENT_CAP) {
                ents[2 * ne] = 0; ents[2 * ne + 1] = 0; ne++;
            }
        }
        koff[t * (KSZ + 1) + KSZ] = ne;
        for (int e0 = tBase; e0 < ne; e0 += EUNIT) {
            int e1 = e0 + EUNIT < ne ? e0 + EUNIT : ne;
            int kb = 0;
            while (kb < KSZ &&
                   !(koff[t * (KSZ + 1) + kb] <= e0 && e0 < koff[t * (KSZ + 1) + kb + 1]))
                kb++;
            if (nu < UCAP) {
                units[nu * 4 + 0] = (u32)t;
                units[nu * 4 + 1] = (u32)e0;
                units[nu * 4 + 2] = (u32)e1;
                units[nu * 4 + 3] = (u32)kb;
                nu++;
            }
        }
    }
    *ne_out = ne;
    return nu;
}

// ---------------------------------------------------------------------------
// Kernel: transpose weights [o][c][k] -> wt[c][k][o] (contiguous o).
// ---------------------------------------------------------------------------
__global__ void transpose_w(const float* __restrict__ wgt, float* __restrict__ wt)
{
    int i = blockIdx.x * blockDim.x + threadIdx.x;
    if (i >= NCH * NCH * KSZ) return;
    int o = i / (NCH * KSZ);
    int rem = i - o * (NCH * KSZ);
    int c = rem / KSZ;
    int k = rem - c * KSZ;
    wt[((size_t)c * KSZ + k) * NCH + o] = wgt[i];
}

// ---------------------------------------------------------------------------
// Main fused kernel. Block = (unit, cg, b); thread owns longitude p.
// Stage x rows (doubled) in LDS; walk the unit's entry range k-segment-wise:
// z accumulated with 4-way ILP over wave-uniform entry loads + lane-consecutive
// LDS gathers; per k, contract z into acc[64] with uniform weight loads.
// Final: 64 atomicAdds into out (zeroed at launch).
// ---------------------------------------------------------------------------
__global__ __launch_bounds__(THREADS, 4) void disco_fused(
    const float* __restrict__ x, const float* __restrict__ wt,
    const uint2* __restrict__ ents, const int* __restrict__ koffG,
    const uint4* __restrict__ units, float* __restrict__ out)
{
    uint4 u = units[blockIdx.x];
    int t = (int)u.x, eBeg = (int)u.y, eEnd = (int)u.z, kBeg = (int)u.w;
    int cg = blockIdx.y, b = blockIdx.z;
    int tid = threadIdx.x;
    int p = tid < NLON ? tid : NLON - 1;
    bool act = tid < NLON;
    __shared__ float xs[NW * XW];
    const int* ko = koffG + t * (KSZ + 1);

    float acc[NCH];
#pragma unroll
    for (int o = 0; o < NCH; o++) acc[o] = 0.f;

    for (int ci = 0; ci < CPG; ci++) {
        int c = cg * CPG + ci;
        __syncthreads();
        const float* xc = x + ((size_t)(b * NCH + c)) * (NLAT * NLON);
#pragma unroll
        for (int w = 0; w < NW; w++) {
            int tw = t - HALF + w;
            int ti = tw < 0 ? 0 : (tw > NLAT - 1 ? NLAT - 1 : tw);
            const float* xr = xc + ti * NLON;
            for (int i = tid; i < XW; i += THREADS) {
                int src = i + 90;
                if (src >= NLON) src -= NLON;
                if (src >= NLON) src -= NLON;
                xs[w * XW + i] = xr[src];
            }
        }
        __syncthreads();

        const float* xp = xs + p;
        int e = eBeg, k = kBeg;
        while (e < eEnd) {
            int kend = ko[k + 1];
            if (kend > eEnd) kend = eEnd;
            float z0 = 0.f, z1 = 0.f, z2 = 0.f, z3 = 0.f;
            for (; e < kend; e += 8) {
                uint2 a0 = ents[e + 0], a1 = ents[e + 1], a2 = ents[e + 2], a3 = ents[e + 3];
                uint2 a4 = ents[e + 4], a5 = ents[e + 5], a6 = ents[e + 6], a7 = ents[e + 7];
                z0 = fmaf(__uint_as_float(a0.y), xp[a0.x], z0);
                z1 = fmaf(__uint_as_float(a1.y), xp[a1.x], z1);
                z2 = fmaf(__uint_as_float(a2.y), xp[a2.x], z2);
                z3 = fmaf(__uint_as_float(a3.y), xp[a3.x], z3);
                z0 = fmaf(__uint_as_float(a4.y), xp[a4.x], z0);
                z1 = fmaf(__uint_as_float(a5.y), xp[a5.x], z1);
                z2 = fmaf(__uint_as_float(a6.y), xp[a6.x], z2);
                z3 = fmaf(__uint_as_float(a7.y), xp[a7.x], z3);
            }
            float zk = (z0 + z1) + (z2 + z3);
            const float* wk = wt + ((size_t)c * KSZ + k) * NCH;
#pragma unroll
            for (int o = 0; o < NCH; o++)
                acc[o] = fmaf(wk[o], zk, acc[o]);
            k++;
            if (k > KSZ) break;  // defensive (host invariant: unreachable)
        }
    }

    if (act) {
        float* op = out + ((size_t)b * NCH * NLAT * NLON) + (size_t)t * NLON + p;
#pragma unroll
        for (int o = 0; o < NCH; o++)
            atomicAdd(op + (size_t)o * (NLAT * NLON), acc[o]);
    }
}

extern "C" void kernel_launch(void* const* d_in, const int* in_sizes, int n_in,
                              void* d_out, int out_size, void* d_ws, size_t ws_size,
                              hipStream_t stream)
{
    const float* x   = (const float*)d_in[0];
    const float* wgt = (const float*)d_in[1];
    char* ws = (char*)d_ws;

    const size_t WT_BYTES = (size_t)NCH * KSZ * NCH * 4;   // 409600, 256-aligned
    float* wt = (float*)ws;
    unsigned char* d_blob = (unsigned char*)(ws + WT_BYTES);

    // Host tables: recomputed identically each call (capture-time only);
    // static blob keeps the pointer valid for graph replay.
    static unsigned char h_blob[ENTS_OFF + (size_t)ENT_CAP * 8];
    int ne = 0;
    int nu = build_tables(h_blob, &ne);
    size_t blob_bytes = (size_t)ENTS_OFF + (size_t)ne * 8;

    hipMemsetAsync(d_out, 0, (size_t)out_size * 4, stream);
    hipMemcpyAsync(d_blob, h_blob, blob_bytes, hipMemcpyHostToDevice, stream);
    transpose_w<<<(NCH * NCH * KSZ + 255) / 256, 256, 0, stream>>>(wgt, wt);

    const uint2* ents  = (const uint2*)(d_blob + ENTS_OFF);
    const int*   koffG = (const int*)(d_blob + KOFF_OFF);
    const uint4* units = (const uint4*)(d_blob + UNITS_OFF);

    disco_fused<<<dim3(nu, CG, NB), THREADS, 0, stream>>>(
        x, wt, ents, koffG, units, (float*)d_out);
}